// Round 1
// baseline (289.068 us; speedup 1.0000x reference)
//
#include <hip/hip_runtime.h>
#include <hip/hip_cooperative_groups.h>

namespace cg = cooperative_groups;

// ViewLearner edge-MLP, single fused cooperative kernel:
//   Phase 1 (UV build): UV[n] = [ x_n @ W1[0:64] + b1 | x_n @ W1[64:128] ] (fp16)
//       one small MFMA GEMM over nodes (sequential rows, no gather).
//   grid.sync()
//   Phase 2 (edge out): out[e] = relu(UV[src][0:64] + UV[dst][64:128]) . W2 + b2
//       8 lanes per edge, pure gather+VALU, grid-stride.
//
// Rationale: removes the 2nd kernel launch + inter-kernel drain from the
// captured graph, and produces a single dispatch whose rocprof counters are
// attributable to our code.

typedef __attribute__((ext_vector_type(8))) short short8;
typedef __attribute__((ext_vector_type(4))) float f32x4;
typedef __attribute__((ext_vector_type(8))) _Float16 half8;

__device__ __forceinline__ unsigned short f2bf_rne(float f) {
    union { float f; unsigned u; } v;
    v.f = f;
    return (unsigned short)((v.u + 0x7FFFu + ((v.u >> 16) & 1u)) >> 16);
}

#define W1T_K 72       // 64 + 8 shorts pad
#define CT_STRIDE 136  // 128 + 8 halfs pad

// LDS: 128*72*2 + 4*16*136*2 = 18432 + 17408 = 35840 B -> 4 blocks/CU (160 KiB)
// launch_bounds(256,4): 4 waves/EU min -> VGPR cap 128; phase-1 restructured
// (B-frags loaded per-nt inside the MFMA loop) to stay well under that.
__global__ __launch_bounds__(256, 4)
void fused(const float* __restrict__ X,
           const int* __restrict__ eidx,
           const float* __restrict__ W1,
           const float* __restrict__ b1,
           const float* __restrict__ W2,
           const float* __restrict__ b2,
           _Float16* __restrict__ UV,
           float* __restrict__ out,
           int nnodes, int ntiles, int E) {
    // B matrix [k<64][j'<128]: j'<64 -> W1[k][j'] (U), j'>=64 -> W1[64+k][j'-64] (V)
    __shared__ __align__(16) unsigned short w1t[128 * W1T_K];
    __shared__ __align__(16) _Float16 cbuf[4][16 * CT_STRIDE];

    const int tid = threadIdx.x;
#pragma unroll
    for (int i = 0; i < 32; ++i) {
        int idx = tid + i * 256;  // 8192 = 128*64 elements of W1, coalesced read
        int r = idx >> 6;         // W1 row (input dim) 0..127
        int col = idx & 63;       // W1 col (hidden)    0..63
        int k = r & 63;
        int jp = col + (r & 64);  // r>=64 -> V half (cols 64..127)
        w1t[jp * W1T_K + k] = f2bf_rne(W1[idx]);
    }
    __syncthreads();

    const int lane = tid & 63;
    const int wid = tid >> 6;
    const int c = lane & 15;
    const int quad = lane >> 4;

    float b1v[8];
#pragma unroll
    for (int nt = 0; nt < 8; ++nt)
        b1v[nt] = (nt < 4) ? b1[nt * 16 + c] : 0.f;  // fold b1 into U half only

    // ---- Phase 1: grid-stride over node tiles (no early return: grid.sync ahead)
    for (int t = blockIdx.x * 4 + wid; t < ntiles; t += gridDim.x * 4) {
        // A row (node) loads: sequential rows, coalesced; convert fp32 -> bf16.
        int n = t * 16 + c;
        n = (n < nnodes) ? n : (nnodes - 1);
        const float* xr = X + (size_t)n * 64 + quad * 8;
        f32x4 x0a = *(const f32x4*)(xr);
        f32x4 x0b = *(const f32x4*)(xr + 4);
        f32x4 x1a = *(const f32x4*)(xr + 32);
        f32x4 x1b = *(const f32x4*)(xr + 36);
        short8 a0, a1;
#pragma unroll
        for (int i = 0; i < 4; ++i) {
            a0[i] = (short)f2bf_rne(x0a[i]);
            a0[4 + i] = (short)f2bf_rne(x0b[i]);
            a1[i] = (short)f2bf_rne(x1a[i]);
            a1[4 + i] = (short)f2bf_rne(x1b[i]);
        }

        // B frags read per-nt from LDS (keeps VGPR < 128 for 4-block residency)
        f32x4 acc[8];
#pragma unroll
        for (int nt = 0; nt < 8; ++nt) {
            short8 bf0 = *(const short8*)&w1t[(nt * 16 + c) * W1T_K + 0 * 32 + quad * 8];
            short8 bf1 = *(const short8*)&w1t[(nt * 16 + c) * W1T_K + 1 * 32 + quad * 8];
            acc[nt] = (f32x4){0.f, 0.f, 0.f, 0.f};
            acc[nt] = __builtin_amdgcn_mfma_f32_16x16x32_bf16(a0, bf0, acc[nt], 0, 0, 0);
            acc[nt] = __builtin_amdgcn_mfma_f32_16x16x32_bf16(a1, bf1, acc[nt], 0, 0, 0);
        }

        // C layout: col j' = nt*16+c, row = quad*4+r. Repack via per-wave LDS
        // region to fp16, then coalesced 4 KB contiguous store.
        _Float16* cb = cbuf[wid];
#pragma unroll
        for (int nt = 0; nt < 8; ++nt)
#pragma unroll
            for (int r = 0; r < 4; ++r)
                cb[(quad * 4 + r) * CT_STRIDE + nt * 16 + c] =
                    (_Float16)(acc[nt][r] + b1v[nt]);

        __builtin_amdgcn_s_waitcnt(0);  // drain ds_writes before cross-lane ds_read

        // lane l copies 32 halfs: global flat g = l*32 + i -> row g/128, col g%128
        const _Float16* rp = &cb[(lane >> 2) * CT_STRIDE + (lane & 3) * 32];
        const f32x4* s4 = (const f32x4*)rp;
        f32x4* dstp = (f32x4*)(UV + (size_t)t * 2048 + lane * 32);
        dstp[0] = s4[0];
        dstp[1] = s4[1];
        dstp[2] = s4[2];
        dstp[3] = s4[3];
        // NOTE: LDS ops per-wave are in-order -> next iter's ds_writes cannot
        // pass this iter's ds_reads; no extra barrier needed (cbuf is per-wave).
    }

    // UV must be visible device-wide (cross-XCD) before any block reads it.
    __threadfence();
    cg::this_grid().sync();

    // ---- Phase 2: grid-stride over edges, 8 lanes per edge
    const int v0 = blockIdx.x * 256 + tid;
    const int j = v0 & 7;  // gsize is a multiple of 8 -> j loop-invariant
    const f32x4 w2a = *(const f32x4*)(W2 + j * 8);
    const f32x4 w2b = *(const f32x4*)(W2 + j * 8 + 4);
    const float b2v = b2[0];
    const int estep = (gridDim.x * 256) >> 3;

    for (int e = v0 >> 3; e < E; e += estep) {
        int sidx = eidx[e];
        int didx = eidx[E + e];

        half8 u = *(const half8*)(UV + (size_t)sidx * 128 + j * 8);
        half8 v = *(const half8*)(UV + (size_t)didx * 128 + 64 + j * 8);

        float acc = 0.f;
#pragma unroll
        for (int i = 0; i < 4; ++i) {
            float h0 = fmaxf((float)u[i] + (float)v[i], 0.f);
            float h1 = fmaxf((float)u[4 + i] + (float)v[4 + i], 0.f);
            acc = fmaf(h0, w2a[i], acc);
            acc = fmaf(h1, w2b[i], acc);
        }
        acc += __shfl_xor(acc, 1, 8);
        acc += __shfl_xor(acc, 2, 8);
        acc += __shfl_xor(acc, 4, 8);
        if (j == 0) out[e] = acc + b2v;
    }
}

extern "C" void kernel_launch(void* const* d_in, const int* in_sizes, int n_in,
                              void* d_out, int out_size, void* d_ws, size_t ws_size,
                              hipStream_t stream) {
    const float* X = (const float*)d_in[0];
    const int* eidx = (const int*)d_in[1];
    const float* W1 = (const float*)d_in[2];
    const float* b1 = (const float*)d_in[3];
    const float* W2 = (const float*)d_in[4];
    const float* b2 = (const float*)d_in[5];
    float* out = (float*)d_out;

    const int nnodes = in_sizes[0] / 64;
    const int E = in_sizes[1] / 2;

    _Float16* UV = (_Float16*)d_ws;  // [ntiles*16][128] fp16, ~12.8 MB

    int ntiles = (nnodes + 15) / 16;

    // Co-residency-safe cooperative grid: blocks/CU from the occupancy API
    // (expected 4 via the 35.8 KB LDS limit), cached across calls.
    static int gridsz = 0;
    if (gridsz == 0) {
        int dev = 0;
        (void)hipGetDevice(&dev);
        hipDeviceProp_t prop;
        (void)hipGetDeviceProperties(&prop, dev);
        int nb = 0;
        (void)hipOccupancyMaxActiveBlocksPerMultiprocessor(&nb, fused, 256, 0);
        if (nb < 1) nb = 1;
        gridsz = nb * prop.multiProcessorCount;
    }

    void* args[] = {(void*)&X, (void*)&eidx, (void*)&W1, (void*)&b1,
                    (void*)&W2, (void*)&b2, (void*)&UV, (void*)&out,
                    (void*)&nnodes, (void*)&ntiles, (void*)&E};
    (void)hipLaunchCooperativeKernel((void*)fused, dim3(gridsz), dim3(256),
                                     args, 0, stream);
}

// Round 2
// 103.003 us; speedup vs baseline: 2.8064x; 2.8064x over previous
//
#include <hip/hip_runtime.h>

// ViewLearner edge-MLP, two-kernel structure (round-0 baseline, proven 104 us):
//   K1 (node_uv): UV[n] = [ x_n @ W1[0:64] + b1 | x_n @ W1[64:128] ]  (fp16, 12.8 MB in ws)
//       -- one small MFMA GEMM over nodes (sequential rows, no gather).
//   K2 (edge_out): out[e] = relu(UV[src][0:64] + UV[dst][64:128]) . W2 + b2
//       -- latency-bound gather. NEW: 2 edges per thread (e, e+E/2) -> 4
//          independent line-coalesced gathers in flight per lane (MLP 2->4),
//          half the thread generations; nt loads for eidx, nt store for out.

typedef __attribute__((ext_vector_type(8))) short short8;
typedef __attribute__((ext_vector_type(4))) float f32x4;
typedef __attribute__((ext_vector_type(8))) _Float16 half8;

__device__ __forceinline__ unsigned short f2bf_rne(float f) {
    union { float f; unsigned u; } v;
    v.f = f;
    return (unsigned short)((v.u + 0x7FFFu + ((v.u >> 16) & 1u)) >> 16);
}

#define W1T_K 72       // 64 + 8 shorts pad
#define CT_STRIDE 136  // 128 + 8 halfs pad

// ---- K1: per-node U|V table via 16x16x32 bf16 MFMA --------------------------
__global__ __launch_bounds__(256)
void node_uv(const float* __restrict__ X,
             const float* __restrict__ W1,
             const float* __restrict__ b1,
             _Float16* __restrict__ UV,
             int nnodes, int ntiles) {
    // B matrix [k<64][j'<128]: j'<64 -> W1[k][j'] (U), j'>=64 -> W1[64+k][j'-64] (V)
    __shared__ __align__(16) unsigned short w1t[128 * W1T_K];
    __shared__ __align__(16) _Float16 cbuf[4][16 * CT_STRIDE];

    const int tid = threadIdx.x;
#pragma unroll
    for (int i = 0; i < 32; ++i) {
        int idx = tid + i * 256;  // 8192 = 128*64 elements of W1, coalesced read
        int r = idx >> 6;         // W1 row (input dim) 0..127
        int col = idx & 63;       // W1 col (hidden)    0..63
        int k = r & 63;
        int jp = col + (r & 64);  // r>=64 -> V half (cols 64..127)
        w1t[jp * W1T_K + k] = f2bf_rne(W1[idx]);
    }
    __syncthreads();

    const int lane = tid & 63;
    const int wid = tid >> 6;
    const int c = lane & 15;
    const int quad = lane >> 4;

    const int t = blockIdx.x * 4 + wid;
    if (t >= ntiles) return;  // wave-uniform

    // B frags: bfrag[nt][kc] = B[k = kc*32+quad*8+j][col = nt*16+c]
    short8 bfrag[8][2];
#pragma unroll
    for (int nt = 0; nt < 8; ++nt)
#pragma unroll
        for (int kc = 0; kc < 2; ++kc)
            bfrag[nt][kc] =
                *(const short8*)&w1t[(nt * 16 + c) * W1T_K + kc * 32 + quad * 8];

    float b1v[8];
#pragma unroll
    for (int nt = 0; nt < 8; ++nt)
        b1v[nt] = (nt < 4) ? b1[nt * 16 + c] : 0.f;  // fold b1 into U half only

    // A row (node) loads: sequential rows, coalesced; convert fp32 -> bf16.
    int n = t * 16 + c;
    n = (n < nnodes) ? n : (nnodes - 1);
    const float* xr = X + (size_t)n * 64 + quad * 8;
    f32x4 x0a = *(const f32x4*)(xr);
    f32x4 x0b = *(const f32x4*)(xr + 4);
    f32x4 x1a = *(const f32x4*)(xr + 32);
    f32x4 x1b = *(const f32x4*)(xr + 36);
    short8 a0, a1;
#pragma unroll
    for (int i = 0; i < 4; ++i) {
        a0[i] = (short)f2bf_rne(x0a[i]);
        a0[4 + i] = (short)f2bf_rne(x0b[i]);
        a1[i] = (short)f2bf_rne(x1a[i]);
        a1[4 + i] = (short)f2bf_rne(x1b[i]);
    }

    f32x4 acc[8];
#pragma unroll
    for (int nt = 0; nt < 8; ++nt) acc[nt] = (f32x4){0.f, 0.f, 0.f, 0.f};
#pragma unroll
    for (int nt = 0; nt < 8; ++nt) {
        acc[nt] = __builtin_amdgcn_mfma_f32_16x16x32_bf16(a0, bfrag[nt][0], acc[nt], 0, 0, 0);
        acc[nt] = __builtin_amdgcn_mfma_f32_16x16x32_bf16(a1, bfrag[nt][1], acc[nt], 0, 0, 0);
    }

    // C layout: col j' = nt*16+c, row = quad*4+r. Repack via per-wave LDS region
    // to fp16, then coalesced 4 KB contiguous store (UV tile rows are contiguous).
    _Float16* cb = cbuf[wid];
#pragma unroll
    for (int nt = 0; nt < 8; ++nt)
#pragma unroll
        for (int r = 0; r < 4; ++r)
            cb[(quad * 4 + r) * CT_STRIDE + nt * 16 + c] =
                (_Float16)(acc[nt][r] + b1v[nt]);

    __builtin_amdgcn_s_waitcnt(0);  // drain ds_writes before cross-lane ds_read

    // lane l copies 32 halfs: global flat g = l*32 + i -> row g/128, col g%128
    const _Float16* rp = &cb[(lane >> 2) * CT_STRIDE + (lane & 3) * 32];
    const f32x4* s4 = (const f32x4*)rp;
    f32x4* dst = (f32x4*)(UV + (size_t)t * 2048 + lane * 32);
    dst[0] = s4[0];
    dst[1] = s4[1];
    dst[2] = s4[2];
    dst[3] = s4[3];
}

// ---- K2: per-edge gather + relu + dot(W2), 2 edges per thread ---------------
__global__ __launch_bounds__(256)
void edge_out(const int* __restrict__ eidx,
              const _Float16* __restrict__ UV,
              const float* __restrict__ W2,
              const float* __restrict__ b2,
              float* __restrict__ out, int E, int Ehalf) {
    int tid = blockIdx.x * 256 + threadIdx.x;
    int e0 = tid >> 3;      // 8 lanes per edge
    int j = tid & 7;        // hidden chunk [j*8, j*8+8)
    if (e0 >= Ehalf) return;
    int e1 = e0 + Ehalf;
    bool has1 = (e1 < E);

    // eidx: single-use stream -> nontemporal (keep L2 for the UV table)
    int s0 = __builtin_nontemporal_load(eidx + e0);
    int d0 = __builtin_nontemporal_load(eidx + E + e0);
    int e1c = has1 ? e1 : e0;
    int s1 = __builtin_nontemporal_load(eidx + e1c);
    int d1 = __builtin_nontemporal_load(eidx + E + e1c);

    // 4 independent 16B gathers; each edge's 8 lanes cover one 128B line.
    half8 u0 = *(const half8*)(UV + (size_t)s0 * 128 + j * 8);
    half8 v0 = *(const half8*)(UV + (size_t)d0 * 128 + 64 + j * 8);
    half8 u1 = *(const half8*)(UV + (size_t)s1 * 128 + j * 8);
    half8 v1 = *(const half8*)(UV + (size_t)d1 * 128 + 64 + j * 8);

    f32x4 w2a = *(const f32x4*)(W2 + j * 8);
    f32x4 w2b = *(const f32x4*)(W2 + j * 8 + 4);
    const float b2v = b2[0];

    float a0 = 0.f, a1 = 0.f;
#pragma unroll
    for (int i = 0; i < 4; ++i) {
        a0 = fmaf(fmaxf((float)u0[i] + (float)v0[i], 0.f), w2a[i], a0);
        a0 = fmaf(fmaxf((float)u0[4 + i] + (float)v0[4 + i], 0.f), w2b[i], a0);
        a1 = fmaf(fmaxf((float)u1[i] + (float)v1[i], 0.f), w2a[i], a1);
        a1 = fmaf(fmaxf((float)u1[4 + i] + (float)v1[4 + i], 0.f), w2b[i], a1);
    }
    a0 += __shfl_xor(a0, 1, 8);
    a0 += __shfl_xor(a0, 2, 8);
    a0 += __shfl_xor(a0, 4, 8);
    a1 += __shfl_xor(a1, 1, 8);
    a1 += __shfl_xor(a1, 2, 8);
    a1 += __shfl_xor(a1, 4, 8);
    if (j == 0) {
        __builtin_nontemporal_store(a0 + b2v, out + e0);
        if (has1) __builtin_nontemporal_store(a1 + b2v, out + e1);
    }
}

extern "C" void kernel_launch(void* const* d_in, const int* in_sizes, int n_in,
                              void* d_out, int out_size, void* d_ws, size_t ws_size,
                              hipStream_t stream) {
    const float* X = (const float*)d_in[0];
    const int* eidx = (const int*)d_in[1];
    const float* W1 = (const float*)d_in[2];
    const float* b1 = (const float*)d_in[3];
    const float* W2 = (const float*)d_in[4];
    const float* b2 = (const float*)d_in[5];
    float* out = (float*)d_out;

    const int nnodes = in_sizes[0] / 64;
    const int E = in_sizes[1] / 2;

    _Float16* UV = (_Float16*)d_ws;  // [nnodes_padded][128] fp16, ~12.8 MB

    const int ntiles = (nnodes + 15) / 16;
    node_uv<<<(ntiles + 3) / 4, 256, 0, stream>>>(X, W1, b1, UV, nnodes, ntiles);

    const int Ehalf = (E + 1) / 2;
    const int nthreads = Ehalf * 8;
    edge_out<<<(nthreads + 255) / 256, 256, 0, stream>>>(eidx, UV, W2, b2, out, E, Ehalf);
}